// Round 2
// baseline (167.827 us; speedup 1.0000x reference)
//
#include <hip/hip_runtime.h>
#include <math.h>

#define NN 648      // code length / variables
#define EE 1944     // edges
#define NCHK 324    // checks, each = 6 consecutive edges
#define BATCH 2048
#define BS 256      // extraction kernels
#define BSM 384     // bp_main: one check per thread (324 < 384), 6 waves
#define ROWS 2      // batch rows per block
#define TL_CLAMP 14.508648f   // 2*atanh(0.999999)

// ---------------------------------------------------------------------------
// Fast transcendentals (hardware v_exp_f32 / v_log_f32 / v_rcp_f32).
// CRITICAL: tanh_half returns 0 IFF x==0 — zero-ness gates the reference's
// cn_update nz-mask semantics (R2 lesson: exp path flushes |x|<~2e-7 -> Taylor
// small path keeps tiny nonzeros nonzero).
// ---------------------------------------------------------------------------
__device__ __forceinline__ float rcp_fast(float x) { return __builtin_amdgcn_rcpf(x); }

__device__ __forceinline__ float tanh_half(float x) {
    // tanh(x/2) = 1 - 2/(e^x + 1): sign-correct, saturates exactly to +/-1.
    float E = __expf(x);
    float big = 1.0f - 2.0f * rcp_fast(E + 1.0f);
    float u = 0.5f * x;
    float small = u * (1.0f - 0.33333334f * u * u);   // |u|<=2^-6, err ~6e-10
    return (fabsf(x) < 0.03125f) ? small : big;
}

__device__ __forceinline__ float sigm(float s) {
    return rcp_fast(1.0f + __expf(-s));
}

// Two-log CN form: ext = Q/a, 2*atanh(ext) = ln2*(log2|a+Q| - log2|a-Q|),
// clamped at +/-2*atanh(0.999999). a-+Q==0 -> +/-inf -> clamp (== ref clamp).
__device__ __forceinline__ float cn_edge(float a, float Q) {
    float t = 0.6931472f * (__log2f(fabsf(a + Q)) - __log2f(fabsf(a - Q)));
    return fminf(fmaxf(t, -TL_CLAMP), TL_CLAMP);
}

// Rare path (exact-zero member / full underflow): reference skip-zero / any_nz
// extrinsic semantics. By-value args: no pointer to a register array (which
// would force scratch); __noinline__ keeps the hot path lean.
__device__ __noinline__ float cn_fallback(float a, float t0, float t1, float t2,
                                          float t3, float t4, float t5) {
    float vv[6] = {t0, t1, t2, t3, t4, t5};
    float P = 1.0f; int cz = 0;
    #pragma unroll
    for (int k = 0; k < 6; k++) {
        if (vv[k] == 0.0f) cz++; else P *= vv[k];
    }
    float ext;
    if (a != 0.0f) ext = (cz >= 5) ? 0.0f : P * rcp_fast(a);
    else           ext = (cz >= 6) ? 0.0f : P;
    ext = fminf(fmaxf(ext, -0.999999f), 0.999999f);
    return 0.6931472f * __log2f((1.0f + ext) * rcp_fast(1.0f - ext));
}

// ---------------------------------------------------------------------------
// Structure extraction (re-run every call; inputs restored pristine each time)
// M_out is [N,E] = M_ev.T: one nonzero (==1.0) per column e, at row var_of[e].
// Each var appears once per permutation layer (layer = e/NN) -> race-free.
// Also emits varc16[e] = var_of[e] as 16-bit (read as packed uint pairs).
// ---------------------------------------------------------------------------
__global__ __launch_bounds__(BS) void extract_struct(
    const float4* __restrict__ M_out4,
    int* __restrict__ var_of, int* __restrict__ varEdge,
    unsigned short* __restrict__ varc16) {
    int t = blockIdx.x * BS + threadIdx.x;
    if (t >= NN * EE / 4) return;
    float4 v = M_out4[t];
    int flat = t * 4;
    int n = flat / EE;
    int e = flat - n * EE;
    if (v.x != 0.0f) { var_of[e]     = n; varEdge[n*3 + (e)    /NN] = e;     varc16[e]     = (unsigned short)n; }
    if (v.y != 0.0f) { var_of[e + 1] = n; varEdge[n*3 + (e + 1)/NN] = e + 1; varc16[e + 1] = (unsigned short)n; }
    if (v.z != 0.0f) { var_of[e + 2] = n; varEdge[n*3 + (e + 2)/NN] = e + 2; varc16[e + 2] = (unsigned short)n; }
    if (v.w != 0.0f) { var_of[e + 3] = n; varEdge[n*3 + (e + 3)/NN] = e + 3; varc16[e + 3] = (unsigned short)n; }
}

// One thread per (matrix, edge): 2 scalar loads each, plus NN threads for W9.
// Weight layout per CHECK: 12 floats (2 per edge) = 3 float4 at float4-index
// 3c (float2-index == e, since edges are check-consecutive). nb packed as
// (eb<<16)|ea per edge.
__global__ __launch_bounds__(BS) void extract_weights(
    const float* __restrict__ W1, const float* __restrict__ W3,
    const float* __restrict__ W5, const float* __restrict__ W7,
    const float* __restrict__ W9,
    const int* __restrict__ var_of, const int* __restrict__ varEdge,
    unsigned* __restrict__ nb6,
    float4* __restrict__ w1q, float4* __restrict__ w3q,
    float4* __restrict__ w5q, float4* __restrict__ w7q,
    float* __restrict__ w9v) {
    int t = blockIdx.x * BS + threadIdx.x;
    if (t < 4 * EE) {
        int m = t / EE;
        int e = t - m * EE;
        int n = var_of[e];
        int e0 = varEdge[3 * n], e1 = varEdge[3 * n + 1], e2 = varEdge[3 * n + 2];
        int ea, eb;
        if (e == e0)      { ea = e1; eb = e2; }
        else if (e == e1) { ea = e0; eb = e2; }
        else              { ea = e0; eb = e1; }
        const float* W = (m == 0) ? W1 : (m == 1) ? W3 : (m == 2) ? W5 : W7;
        size_t row = (size_t)e * EE;
        float2 w = make_float2(W[row + ea], W[row + eb]);
        float4* dq = (m == 0) ? w1q : (m == 1) ? w3q : (m == 2) ? w5q : w7q;
        ((float2*)dq)[e] = w;
        if (m == 0) nb6[e] = (unsigned)ea | ((unsigned)eb << 16);
    } else if (t < 4 * EE + NN) {
        int n = t - 4 * EE;
        #pragma unroll
        for (int k = 0; k < 3; k++) {
            int e = varEdge[3 * n + k];
            w9v[3 * n + k] = W9[(size_t)n * EE + e];
        }
    }
}

// ---------------------------------------------------------------------------
// Main BP kernel: one block per TWO batch rows, ONE CHECK PER THREAD (x2 rows).
// Rationale (R1): grid 1024 = 256 CU x 4 blocks/CU (LDS-limited) -> exactly one
// scheduling round (old: 2048 blocks @ 5/CU = 1.6 rounds, 60%-full tail).
// Two rows/thread doubles ILP on the v_exp/v_log dependence chains and
// amortizes all index/weight loads (identical across rows) 2x.
// All 12 check members (te0/te1) live in registers -> no te LDS array.
// tl double-buffered in LDS -> 1 barrier per layer (6 total).
// LDS: llr 5.2 KB + 2*2*tl 31.1 KB = 36.3 KB -> 4 blocks/CU, 24 waves/CU.
// __launch_bounds__(384,6): VGPR cap ~85 for 24 waves/CU occupancy.
// ---------------------------------------------------------------------------
__global__ __launch_bounds__(BSM, 6) void bp_main(
    const float* __restrict__ x,
    const unsigned* __restrict__ varc,   // ushort[EE] viewed as uint[EE/2]
    const unsigned* __restrict__ nb6,    // uint[EE]: (eb<<16)|ea
    const int* __restrict__ varEdge,     // [3*NN]
    const float4* __restrict__ w1q, const float4* __restrict__ w3q,
    const float4* __restrict__ w5q, const float4* __restrict__ w7q,
    const float* __restrict__ w9v,
    float* __restrict__ out) {
    __shared__ __align__(16) float llr_s[ROWS * NN];   // [r*NN + n]
    __shared__ __align__(16) float tlA[ROWS * EE];     // [r*EE + e]
    __shared__ __align__(16) float tlB[ROWS * EE];
    const int b0 = blockIdx.x * ROWS;
    const int tid = threadIdx.x;

    // llr load: rows b0,b0+1 are contiguous -> 648 float2, coalesced
    {
        const float2* xr2 = (const float2*)(x + (size_t)b0 * NN);
        float2* ls2 = (float2*)llr_s;
        #pragma unroll
        for (int j = 0; j < 2; j++) {
            int i = tid + j * BSM;
            if (i < NN) ls2[i] = xr2[i];   // ROWS*NN/2 = NN float2 total
        }
    }
    __syncthreads();

    const bool ck = tid < NCHK;
    const int c = tid;
    float lb0[6], lb1[6];   // llr at this check's 6 variables, both rows
    unsigned nbp[6];        // packed extrinsic same-var neighbor edge ids
    float te0[6], te1[6];   // check members, both rows — REGISTERS

    if (ck) {
        #pragma unroll
        for (int j = 0; j < 3; j++) {
            unsigned vv = varc[3 * c + j];
            int va = vv & 0xffffu, vb = vv >> 16;
            lb0[2 * j]     = llr_s[va];
            lb0[2 * j + 1] = llr_s[vb];
            lb1[2 * j]     = llr_s[NN + va];
            lb1[2 * j + 1] = llr_s[NN + vb];
        }
        #pragma unroll
        for (int j = 0; j < 6; j++) {
            nbp[j] = nb6[6 * c + j];
            te0[j] = tanh_half(lb0[j]);   // iter 0: te = tanh(0.5*llr[var])
            te1[j] = tanh_half(lb1[j]);
        }
    }
    // marg-out offsets cached (also reused by W9 epilogue)
    int m0[2], m1[2], m2[2];
    #pragma unroll
    for (int j = 0; j < 2; j++) {
        int n = tid + j * BSM;
        if (n < NN) {
            m0[j] = varEdge[3 * n]; m1[j] = varEdge[3 * n + 1];
            m2[j] = varEdge[3 * n + 2];
        } else { m0[j] = m1[j] = m2[j] = 0; }
    }

    auto cn_store = [&](float* dst) {    // dst: row0 at +0, row1 at +EE
        float Q0 = ((te0[0] * te0[1]) * (te0[2] * te0[3])) * (te0[4] * te0[5]);
        float* d0 = dst + 6 * c;
        if (__builtin_expect(Q0 != 0.0f, 1)) {
            #pragma unroll
            for (int j = 0; j < 6; j++) d0[j] = cn_edge(te0[j], Q0);
        } else {
            #pragma unroll
            for (int j = 0; j < 6; j++)
                d0[j] = cn_fallback(te0[j], te0[0], te0[1], te0[2], te0[3], te0[4], te0[5]);
        }
        float Q1 = ((te1[0] * te1[1]) * (te1[2] * te1[3])) * (te1[4] * te1[5]);
        float* d1 = dst + EE + 6 * c;
        if (__builtin_expect(Q1 != 0.0f, 1)) {
            #pragma unroll
            for (int j = 0; j < 6; j++) d1[j] = cn_edge(te1[j], Q1);
        } else {
            #pragma unroll
            for (int j = 0; j < 6; j++)
                d1[j] = cn_fallback(te1[j], te1[0], te1[1], te1[2], te1[3], te1[4], te1[5]);
        }
    };
    auto marg = [&](const float* tl, float* dst) {   // dst: row b0; row b0+1 at +NN
        #pragma unroll
        for (int j = 0; j < 2; j++) {
            int n = tid + j * BSM;
            if (n < NN) {
                dst[n]      = sigm(llr_s[n]      + tl[m0[j]]      + tl[m1[j]]      + tl[m2[j]]);
                dst[NN + n] = sigm(llr_s[NN + n] + tl[EE + m0[j]] + tl[EE + m1[j]] + tl[EE + m2[j]]);
            }
        }
    };

    if (ck) cn_store(tlA);
    __syncthreads();
    // out1 -> chunk 4 (return order: out5,out4,out3,out2,out1)
    marg(tlA, out + ((size_t)(4 * BATCH) + b0) * NN);

    const float4* wqs[4] = {w1q, w3q, w5q, w7q};
    #pragma unroll
    for (int L = 0; L < 4; L++) {
        const float4* __restrict__ wq = wqs[L];
        const float* tlc = (L & 1) ? tlB : tlA;   // CN_{L-1} output
        float* tln = (L & 1) ? tlA : tlB;         // CN_L output
        if (ck) {
            float4 wa = wq[3 * c], wb = wq[3 * c + 1], wc = wq[3 * c + 2];
            float w[12] = {wa.x, wa.y, wa.z, wa.w, wb.x, wb.y, wb.z, wb.w,
                           wc.x, wc.y, wc.z, wc.w};
            // VN: pre = w0*tl[ea] + w1*tl[eb] + llr[var]; te = tanh(pre/2)
            // Same weights/indices serve both rows (graph is batch-invariant).
            #pragma unroll
            for (int j = 0; j < 6; j++) {
                int ea = nbp[j] & 0xffffu, eb = nbp[j] >> 16;
                float pre0 = fmaf(w[2 * j], tlc[ea],
                             fmaf(w[2 * j + 1], tlc[eb], lb0[j]));
                float pre1 = fmaf(w[2 * j], tlc[EE + ea],
                             fmaf(w[2 * j + 1], tlc[EE + eb], lb1[j]));
                te0[j] = tanh_half(pre0);
                te1[j] = tanh_half(pre1);
            }
            cn_store(tln);   // writes buffer nobody reads until next barrier
        }
        __syncthreads();
        if (L < 3) {
            // out2->chunk3, out3->chunk2, out4->chunk1
            marg(tln, out + ((size_t)((3 - L) * BATCH) + b0) * NN);
        } else {
            // out5 -> chunk 0: sigmoid(t@W9.T + llr)   (B4 = I)
            #pragma unroll
            for (int j = 0; j < 2; j++) {
                int n = tid + j * BSM;
                if (n < NN) {
                    float s0 = llr_s[n]
                             + w9v[3 * n]     * tln[m0[j]]
                             + w9v[3 * n + 1] * tln[m1[j]]
                             + w9v[3 * n + 2] * tln[m2[j]];
                    out[(size_t)b0 * NN + n] = sigm(s0);
                    float s1 = llr_s[NN + n]
                             + w9v[3 * n]     * tln[EE + m0[j]]
                             + w9v[3 * n + 1] * tln[EE + m1[j]]
                             + w9v[3 * n + 2] * tln[EE + m2[j]];
                    out[((size_t)b0 + 1) * NN + n] = sigm(s1);
                }
            }
        }
    }
}

// ---------------------------------------------------------------------------
extern "C" void kernel_launch(void* const* d_in, const int* in_sizes, int n_in,
                              void* d_out, int out_size, void* d_ws, size_t ws_size,
                              hipStream_t stream) {
    const float* x     = (const float*)d_in[0];
    const float* M_out = (const float*)d_in[3];
    const float* W1    = (const float*)d_in[5];
    const float* W3    = (const float*)d_in[6];
    const float* W5    = (const float*)d_in[7];
    const float* W7    = (const float*)d_in[8];
    const float* W9    = (const float*)d_in[9];
    // d_in[1]=M_first, d_in[2]=M_cn (patterns implied by check structure),
    // d_in[4]=bias_matrix (values 1.0), d_in[10..14]=B0..B4 (identity).
    float* out = (float*)d_out;

    char* ws = (char*)d_ws;                    // 16B-aligned base
    float4* w1q     = (float4*)ws;         ws += (EE / 2) * 16;
    float4* w3q     = (float4*)ws;         ws += (EE / 2) * 16;
    float4* w5q     = (float4*)ws;         ws += (EE / 2) * 16;
    float4* w7q     = (float4*)ws;         ws += (EE / 2) * 16;
    int*    var_of  = (int*)ws;            ws += EE * 4;
    int*    varEdge = (int*)ws;            ws += NN * 3 * 4;
    float*  w9v     = (float*)ws;          ws += NN * 3 * 4;
    unsigned* nb6   = (unsigned*)ws;       ws += EE * 4;
    unsigned short* varc16 = (unsigned short*)ws; ws += EE * 2;

    const int tot4 = NN * EE / 4;
    extract_struct<<<(tot4 + BS - 1) / BS, BS, 0, stream>>>(
        (const float4*)M_out, var_of, varEdge, varc16);
    const int totW = 4 * EE + NN;
    extract_weights<<<(totW + BS - 1) / BS, BS, 0, stream>>>(
        W1, W3, W5, W7, W9, var_of, varEdge, nb6, w1q, w3q, w5q, w7q, w9v);
    bp_main<<<BATCH / ROWS, BSM, 0, stream>>>(
        x, (const unsigned*)varc16, nb6, varEdge, w1q, w3q, w5q, w7q, w9v, out);
}

// Round 4
// 165.619 us; speedup vs baseline: 1.0133x; 1.0133x over previous
//
#include <hip/hip_runtime.h>
#include <math.h>

#define NN 648      // code length / variables
#define EE 1944     // edges
#define NCHK 324    // checks, each = 6 consecutive edges
#define BATCH 2048
#define BS 256      // extraction kernels
#define BSM 384     // bp_main: one check per thread (324 < 384), 6 waves
#define ROWS 2      // batch rows per block (row-interleaved in LDS)
#define TL_CLAMP 14.508648f   // 2*atanh(0.999999)

// ---------------------------------------------------------------------------
// Fast transcendentals (hardware v_exp_f32 / v_log_f32 / v_rcp_f32).
// CRITICAL: tanh_half returns 0 IFF x==0 — zero-ness gates the reference's
// cn_update nz-mask semantics (exp path flushes |x|<~2e-7 -> Taylor small
// path keeps tiny nonzeros nonzero).
// ---------------------------------------------------------------------------
__device__ __forceinline__ float rcp_fast(float x) { return __builtin_amdgcn_rcpf(x); }

__device__ __forceinline__ float tanh_half(float x) {
    // tanh(x/2) = 1 - 2/(e^x + 1): sign-correct, saturates exactly to +/-1.
    float E = __expf(x);
    float big = 1.0f - 2.0f * rcp_fast(E + 1.0f);
    float u = 0.5f * x;
    float small = u * (1.0f - 0.33333334f * u * u);   // |u|<=2^-6, err ~6e-10
    return (fabsf(x) < 0.03125f) ? small : big;
}

__device__ __forceinline__ float sigm(float s) {
    return rcp_fast(1.0f + __expf(-s));
}

// Two-log CN form: ext = Q/a, 2*atanh(ext) = ln2*(log2|a+Q| - log2|a-Q|),
// clamped at +/-2*atanh(0.999999). a-+Q==0 -> +/-inf -> clamp (== ref clamp).
__device__ __forceinline__ float cn_edge(float a, float Q) {
    float t = 0.6931472f * (__log2f(fabsf(a + Q)) - __log2f(fabsf(a - Q)));
    return fminf(fmaxf(t, -TL_CLAMP), TL_CLAMP);
}

// Rare path (exact-zero member / full underflow): reference skip-zero / any_nz
// extrinsic semantics. By-value args: no pointer to a register array (which
// would force scratch); __noinline__ keeps the hot path lean.
__device__ __noinline__ float cn_fallback(float a, float t0, float t1, float t2,
                                          float t3, float t4, float t5) {
    float vv[6] = {t0, t1, t2, t3, t4, t5};
    float P = 1.0f; int cz = 0;
    #pragma unroll
    for (int k = 0; k < 6; k++) {
        if (vv[k] == 0.0f) cz++; else P *= vv[k];
    }
    float ext;
    if (a != 0.0f) ext = (cz >= 5) ? 0.0f : P * rcp_fast(a);
    else           ext = (cz >= 6) ? 0.0f : P;
    ext = fminf(fmaxf(ext, -0.999999f), 0.999999f);
    return 0.6931472f * __log2f((1.0f + ext) * rcp_fast(1.0f - ext));
}

// ---------------------------------------------------------------------------
// Structure extraction (re-run every call; inputs restored pristine each time)
// M_out is [N,E] = M_ev.T: one nonzero (==1.0) per column e, at row var_of[e].
// Each var appears once per permutation layer (layer = e/NN) -> race-free.
// ---------------------------------------------------------------------------
__global__ __launch_bounds__(BS) void extract_struct(
    const float4* __restrict__ M_out4,
    int* __restrict__ var_of, int* __restrict__ varEdge) {
    int t = blockIdx.x * BS + threadIdx.x;
    if (t >= NN * EE / 4) return;
    float4 v = M_out4[t];
    int flat = t * 4;
    int n = flat / EE;
    int e = flat - n * EE;
    if (v.x != 0.0f) { var_of[e]     = n; varEdge[n*3 + (e)    /NN] = e;     }
    if (v.y != 0.0f) { var_of[e + 1] = n; varEdge[n*3 + (e + 1)/NN] = e + 1; }
    if (v.z != 0.0f) { var_of[e + 2] = n; varEdge[n*3 + (e + 2)/NN] = e + 2; }
    if (v.w != 0.0f) { var_of[e + 3] = n; varEdge[n*3 + (e + 3)/NN] = e + 3; }
}

// One thread per (matrix, edge): 2 scalar loads each, plus NN threads for W9.
// Weight layout per CHECK: 12 floats (2 per edge) = 3 float4 (float2-index == e,
// edges are check-consecutive). w0 pairs the LOWER-slot neighbor, w1 the higher
// (ea,eb ascend in slot order) — matches bp_main's derived (kA,kB) rule.
// vnb[e] = 4*var_of[e] + slot(e), slot = e/NN: the var-major LDS address.
__global__ __launch_bounds__(BS) void extract_weights(
    const float* __restrict__ W1, const float* __restrict__ W3,
    const float* __restrict__ W5, const float* __restrict__ W7,
    const float* __restrict__ W9,
    const int* __restrict__ var_of, const int* __restrict__ varEdge,
    unsigned* __restrict__ vnb,
    float4* __restrict__ w1q, float4* __restrict__ w3q,
    float4* __restrict__ w5q, float4* __restrict__ w7q,
    float* __restrict__ w9v) {
    int t = blockIdx.x * BS + threadIdx.x;
    if (t < 4 * EE) {
        int m = t / EE;
        int e = t - m * EE;
        int n = var_of[e];
        int e0 = varEdge[3 * n], e1 = varEdge[3 * n + 1], e2 = varEdge[3 * n + 2];
        int ea, eb;
        if (e == e0)      { ea = e1; eb = e2; }   // own slot 0 -> neighbors (1,2)
        else if (e == e1) { ea = e0; eb = e2; }   // own slot 1 -> neighbors (0,2)
        else              { ea = e0; eb = e1; }   // own slot 2 -> neighbors (0,1)
        const float* W = (m == 0) ? W1 : (m == 1) ? W3 : (m == 2) ? W5 : W7;
        size_t row = (size_t)e * EE;
        float2 w = make_float2(W[row + ea], W[row + eb]);
        float4* dq = (m == 0) ? w1q : (m == 1) ? w3q : (m == 2) ? w5q : w7q;
        ((float2*)dq)[e] = w;
        if (m == 0) vnb[e] = (unsigned)(4 * n + e / NN);
    } else if (t < 4 * EE + NN) {
        int n = t - 4 * EE;
        #pragma unroll
        for (int k = 0; k < 3; k++) {
            int e = varEdge[3 * n + k];
            w9v[3 * n + k] = W9[(size_t)n * EE + e];   // slot-k ordered
        }
    }
}

// ---------------------------------------------------------------------------
// Main BP kernel, R3 layout: CN outputs live VAR-MAJOR + ROW-INTERLEAVED in
// LDS: tlv[4*v + k] = float2{row0,row1}, k = slot 0..2 (pad at k=3).
// Why (R2 post-mortem): the edge-major layout needed 3 randomly-scattered
// ds_read_b32 per edge per layer (VN gathers + marg gathers) — 4.19M LDS
// bank-conflict cycles and a 6x latency gap over the pipe floors.  Var-major:
//   - VN gather  = 1 b128 + 1 b64 per member, serving BOTH rows (neighbor
//     slots kA,kB derive from own slot k: always the ascending other-two).
//   - marg       = 1 b128 + 1 b64 per var, consecutive lanes — perfectly
//     banked; nb6/varEdge tables & m0..m2 regs gone.
//   - only scatter left: 6 b64 CN writes per check (1 per edge, both rows).
// Single-buffered tlv -> 2 barriers/stage (9 total), LDS 25.3 KB ->
// 5 blocks/CU (wave-capped), grid 1024 = ONE dispatch round.
// ---------------------------------------------------------------------------
__global__ __launch_bounds__(BSM, 8) void bp_main(
    const float* __restrict__ x,
    const unsigned* __restrict__ vnb_g,  // uint[EE]: 4*var + slot
    const float4* __restrict__ w1q, const float4* __restrict__ w3q,
    const float4* __restrict__ w5q, const float4* __restrict__ w7q,
    const float* __restrict__ w9v,
    float* __restrict__ out) {
    __shared__ __align__(16) float2 llr2[NN];      // {row0,row1} llr
    __shared__ __align__(16) float2 tlv[4 * NN];   // [4v+k] = {row0,row1}
    const int b0 = blockIdx.x * ROWS;
    const int tid = threadIdx.x;

    {   // llr load, row-interleaved: two coalesced streams
        const float* x0 = x + (size_t)b0 * NN;
        for (int i = tid; i < NN; i += BSM)
            llr2[i] = make_float2(x0[i], x0[NN + i]);
    }
    __syncthreads();

    const bool ck = tid < NCHK;
    const int c = tid;
    float lb0[6], lb1[6];   // llr at this check's 6 member vars, both rows
    float te0[6], te1[6];   // tanh'd VN outputs (check members) — registers
    unsigned vb[6];         // 4*v + k per member

    if (ck) {
        #pragma unroll
        for (int j = 0; j < 6; j++) {
            vb[j] = vnb_g[6 * c + j];
            float2 l = llr2[vb[j] >> 2];
            lb0[j] = l.x; lb1[j] = l.y;
            te0[j] = tanh_half(lb0[j]);   // stage 0: te = tanh(0.5*llr[var])
            te1[j] = tanh_half(lb1[j]);
        }
    }

    auto cn_store = [&]() {   // 6 scattered b64 writes (the one scatter/layer)
        float Q0 = ((te0[0]*te0[1])*(te0[2]*te0[3]))*(te0[4]*te0[5]);
        float Q1 = ((te1[0]*te1[1])*(te1[2]*te1[3]))*(te1[4]*te1[5]);
        if (__builtin_expect((Q0 != 0.0f) & (Q1 != 0.0f), 1)) {
            #pragma unroll
            for (int j = 0; j < 6; j++)
                tlv[vb[j]] = make_float2(cn_edge(te0[j], Q0),
                                         cn_edge(te1[j], Q1));
        } else {
            #pragma unroll
            for (int j = 0; j < 6; j++) {
                float r0 = (Q0 != 0.0f) ? cn_edge(te0[j], Q0)
                    : cn_fallback(te0[j], te0[0], te0[1], te0[2], te0[3], te0[4], te0[5]);
                float r1 = (Q1 != 0.0f) ? cn_edge(te1[j], Q1)
                    : cn_fallback(te1[j], te1[0], te1[1], te1[2], te1[3], te1[4], te1[5]);
                tlv[vb[j]] = make_float2(r0, r1);
            }
        }
    };
    auto marg = [&](float* dst) {   // wide, consecutive-lane reads
        #pragma unroll
        for (int j = 0; j < 2; j++) {
            int n = tid + j * BSM;
            if (n < NN) {
                float4 q = *(const float4*)&tlv[4 * n];  // {r0k0,r1k0,r0k1,r1k1}
                float2 p = tlv[4 * n + 2];               // {r0k2,r1k2}
                float2 l = llr2[n];
                dst[n]      = sigm(l.x + (q.x + q.z) + p.x);
                dst[NN + n] = sigm(l.y + (q.y + q.w) + p.y);
            }
        }
    };

    if (ck) cn_store();          // CN stage 0
    __syncthreads();
    // out1 -> chunk 4 (return order: out5,out4,out3,out2,out1)
    marg(out + ((size_t)(4 * BATCH) + b0) * NN);

    const float4* wqs[4] = {w1q, w3q, w5q, w7q};
    #pragma unroll
    for (int s = 0; s < 4; s++) {
        const float4* __restrict__ wq = wqs[s];
        if (ck) {
            float4 wa = wq[3 * c], wb = wq[3 * c + 1], wc = wq[3 * c + 2];
            float w[12] = {wa.x, wa.y, wa.z, wa.w, wb.x, wb.y, wb.z, wb.w,
                           wc.x, wc.y, wc.z, wc.w};
            // VN: pre = w0*tl[neighbor kA] + w1*tl[neighbor kB] + llr[var]
            // kA,kB = ascending other-two of own slot k (matches extraction).
            #pragma unroll
            for (int j = 0; j < 6; j++) {
                unsigned a = vb[j];
                int k = a & 3;
                const float2* basep = &tlv[a & ~3u];
                float4 q = *(const float4*)basep;        // {r0k0,r1k0,r0k1,r1k1}
                float2 p = basep[2];                     // {r0k2,r1k2}
                float cA0 = (k == 0) ? q.z : q.x;        // kA = (k==0)?1:0
                float cA1 = (k == 0) ? q.w : q.y;
                float cB0 = (k == 2) ? q.z : p.x;        // kB = (k==2)?1:2
                float cB1 = (k == 2) ? q.w : p.y;
                te0[j] = tanh_half(fmaf(w[2*j], cA0, fmaf(w[2*j+1], cB0, lb0[j])));
                te1[j] = tanh_half(fmaf(w[2*j], cA1, fmaf(w[2*j+1], cB1, lb1[j])));
            }
        }
        __syncthreads();          // all tlv reads (marg + VN) of stage s done
        if (ck) cn_store();       // CN stage s+1 overwrites tlv
        __syncthreads();          // stage s+1 visible
        if (s < 3) {
            // out2->chunk3, out3->chunk2, out4->chunk1
            marg(out + ((size_t)((3 - s) * BATCH) + b0) * NN);
        } else {
            // out5 -> chunk 0: sigmoid(t@W9.T + llr)   (B4 = I)
            #pragma unroll
            for (int j2 = 0; j2 < 2; j2++) {
                int n = tid + j2 * BSM;
                if (n < NN) {
                    float4 q = *(const float4*)&tlv[4 * n];
                    float2 p = tlv[4 * n + 2];
                    float2 l = llr2[n];
                    float u0 = w9v[3*n], u1 = w9v[3*n+1], u2 = w9v[3*n+2];
                    out[(size_t)b0 * NN + n]       = sigm(l.x + u0*q.x + u1*q.z + u2*p.x);
                    out[((size_t)b0 + 1) * NN + n] = sigm(l.y + u0*q.y + u1*q.w + u2*p.y);
                }
            }
        }
    }
}

// ---------------------------------------------------------------------------
extern "C" void kernel_launch(void* const* d_in, const int* in_sizes, int n_in,
                              void* d_out, int out_size, void* d_ws, size_t ws_size,
                              hipStream_t stream) {
    const float* x     = (const float*)d_in[0];
    const float* M_out = (const float*)d_in[3];
    const float* W1    = (const float*)d_in[5];
    const float* W3    = (const float*)d_in[6];
    const float* W5    = (const float*)d_in[7];
    const float* W7    = (const float*)d_in[8];
    const float* W9    = (const float*)d_in[9];
    // d_in[1]=M_first, d_in[2]=M_cn (patterns implied by check structure),
    // d_in[4]=bias_matrix (values 1.0), d_in[10..14]=B0..B4 (identity).
    float* out = (float*)d_out;

    char* ws = (char*)d_ws;                    // 16B-aligned base
    float4* w1q     = (float4*)ws;         ws += (EE / 2) * 16;
    float4* w3q     = (float4*)ws;         ws += (EE / 2) * 16;
    float4* w5q     = (float4*)ws;         ws += (EE / 2) * 16;
    float4* w7q     = (float4*)ws;         ws += (EE / 2) * 16;
    int*    var_of  = (int*)ws;            ws += EE * 4;
    int*    varEdge = (int*)ws;            ws += NN * 3 * 4;
    float*  w9v     = (float*)ws;          ws += NN * 3 * 4;
    unsigned* vnb   = (unsigned*)ws;       ws += EE * 4;

    const int tot4 = NN * EE / 4;
    extract_struct<<<(tot4 + BS - 1) / BS, BS, 0, stream>>>(
        (const float4*)M_out, var_of, varEdge);
    const int totW = 4 * EE + NN;
    extract_weights<<<(totW + BS - 1) / BS, BS, 0, stream>>>(
        W1, W3, W5, W7, W9, var_of, varEdge, vnb, w1q, w3q, w5q, w7q, w9v);
    bp_main<<<BATCH / ROWS, BSM, 0, stream>>>(
        x, vnb, w1q, w3q, w5q, w7q, w9v, out);
}